// Round 1
// baseline (319.070 us; speedup 1.0000x reference)
//
#include <hip/hip_runtime.h>
#include <hip/hip_bf16.h>
#include <stdint.h>

typedef unsigned short u16;
typedef __bf16 bf16x8 __attribute__((ext_vector_type(8)));
typedef float f32x4 __attribute__((ext_vector_type(4)));

#define S_LEN 2048
#define BATCH 2
#define NHEADS 16
#define NGROUPS 4
#define DHEAD 128
#define QKV_W 3072   // fused projection width: 2048 q + 1024 kv

__device__ __forceinline__ float bf2f(u16 u) {
  union { uint32_t i; float f; } v; v.i = ((uint32_t)u) << 16; return v.f;
}
__device__ __forceinline__ u16 f2bf(float f) {
  union { float f; uint32_t i; } v; v.f = f;
  uint32_t r = v.i + 0x7FFF + ((v.i >> 16) & 1);
  return (u16)(r >> 16);
}
__device__ __forceinline__ void llds16(const void* g, void* l) {
  __builtin_amdgcn_global_load_lds(
      (const __attribute__((address_space(1))) uint32_t*)g,
      (__attribute__((address_space(3))) uint32_t*)l, 16, 0, 0);
}

__device__ __forceinline__ void store_out(u16* C, long i, float v) { C[i] = f2bf(v); }
__device__ __forceinline__ void store_out(float* C, long i, float v) { C[i] = v; }

// ---------------- RoPE tables: cos/sin (S_LEN x 64) fp32 ----------------
__global__ void rope_tables_k(float* __restrict__ cosT, float* __restrict__ sinT) {
  int i = blockIdx.x * 256 + threadIdx.x;
  int s = i >> 6, j = i & 63;
  float inv = exp2f(-(float)j * 0.20762050593045983f);  // 10000^(-j/64)
  float ang = (float)s * inv;
  float sv, cv;
  sincosf(ang, &sv, &cv);
  cosT[i] = cv; sinT[i] = sv;
}

// ---------------- fp32 -> bf16 elementwise ----------------
__global__ void cvt_f32_bf16(const float* __restrict__ in, u16* __restrict__ out) {
  long i = ((long)blockIdx.x * 256 + threadIdx.x) * 4;
  float4 v = *(const float4*)(in + i);
  ushort4 o;
  o.x = f2bf(v.x); o.y = f2bf(v.y); o.z = f2bf(v.z); o.w = f2bf(v.w);
  *(ushort4*)(out + i) = o;
}

// -------- fp32 (R x C) -> bf16 transpose (C x R) --------
__global__ void transpose_f32_bf16(const float* __restrict__ in, u16* __restrict__ out,
                                   int R, int C) {
  __shared__ u16 tile[32][33];
  int c0 = blockIdx.x * 32, r0 = blockIdx.y * 32;
  int tx = threadIdx.x, ty = threadIdx.y;  // 32 x 8
  for (int i = 0; i < 32; i += 8)
    tile[ty + i][tx] = f2bf(in[(long)(r0 + ty + i) * C + c0 + tx]);
  __syncthreads();
  for (int i = 0; i < 32; i += 8)
    out[(long)(c0 + ty + i) * R + r0 + tx] = tile[tx][ty + i];
}

// ================= 256x256 8-phase GEMM  C = A * B^T =================
// BM=BN=256, BK=64, 512 threads (8 waves, 2M x 4N), LDS 128 KiB dbuf.
// st_16x32 LDS swizzle (both sides: inverse-swizzled global src for
// global_load_lds + swizzled ds_read). Counted vmcnt(8) once per K-tile,
// never drained in steady state; K-tile m+2 staged during phases 2/3 of
// K-tile m (B halves after their last read at phase 1, A halves after
// phase 2). setprio(1) around each 16-MFMA cluster.

#define GFENCE() asm volatile("" ::: "memory")
#define MIDBAR() do { GFENCE(); __builtin_amdgcn_s_barrier(); \
    asm volatile("s_waitcnt lgkmcnt(0)" ::: "memory"); } while (0)
#define ENDBAR() do { GFENCE(); __builtin_amdgcn_s_barrier(); GFENCE(); } while (0)

// LDS half layout: 128 rows x 64 cols bf16, subtiled [rb 0..7][cb 0..1] into
// 16x32 subtiles (1024 B each); within subtile byte b = r*64 + c*2,
// swizzled b ^= ((r>>3)&1)<<5.
__device__ __forceinline__ bf16x8 frag_ld(const __bf16* h, int wrow, int kk, int quad) {
  int b = ((wrow & 15) << 6) | (quad << 4);
  b ^= ((wrow >> 3) & 1) << 5;
  int off = ((((wrow >> 4) << 1) | kk) << 10) | b;   // bytes within 16 KiB half
  return *(const bf16x8*)((const char*)h + off);
}

// Stage one 128x64 half-tile (16 KiB): 2 global_load_lds per thread.
// Thread t, issue i covers linear LDS bytes i*8192 + t*16; global source is
// the inverse-swizzle image so LDS content matches frag_ld's layout.
__device__ __forceinline__ void stage_half(const u16* __restrict__ g, int K,
                                           __bf16* lhalf, int wv, int lane) {
  int bsrc = (lane << 4) ^ (((lane >> 5) & 1) << 5);
  int r = bsrc >> 6, c = (bsrc & 63) >> 1;
  int cb = (wv & 1) << 5;
  llds16(g + (long)((wv >> 1) * 16 + r) * K + cb + c,
         lhalf + wv * 512 + lane * 8);
  llds16(g + (long)((4 + (wv >> 1)) * 16 + r) * K + cb + c,
         lhalf + 4096 + wv * 512 + lane * 8);
}

template <typename OutT>
__global__ __launch_bounds__(512) void gemm_bt8(
    const u16* __restrict__ A, const u16* __restrict__ Bt, OutT* __restrict__ C,
    int M, int N, int K) {
  __shared__ __align__(16) __bf16 lds[2][2][16384];  // [buf][A,B][256*64] = 128 KiB
  const int tid = threadIdx.x;
  const int wv = tid >> 6, lane = tid & 63;
  const int quad = lane >> 4, l16 = lane & 15;
  const int wr = wv >> 2, wc = wv & 3;   // wave grid: 2 (M) x 4 (N)

  // XCD-aware block swizzle (grid counts here are multiples of 8)
  const int nwg = gridDim.x * gridDim.y;
  const int orig = blockIdx.y * gridDim.x + blockIdx.x;
  const int swz = (orig & 7) * (nwg >> 3) + (orig >> 3);
  const int bx = swz % gridDim.x, by = swz / gridDim.x;
  const int bm = by * 256, bn = bx * 256;

  const u16* Abase = A + (long)bm * K;
  const u16* Bbase = Bt + (long)bn * K;
  const int NT = K >> 6;

  f32x4 acc[8][4] = {};

  // ---- prologue: K-tile 0 -> buf0 first, then K-tile 1 -> buf1 ----
  stage_half(Abase, K, &lds[0][0][0], wv, lane);
  stage_half(Abase + (long)128 * K, K, &lds[0][0][8192], wv, lane);
  stage_half(Bbase, K, &lds[0][1][0], wv, lane);
  stage_half(Bbase + (long)128 * K, K, &lds[0][1][8192], wv, lane);
  stage_half(Abase + 64, K, &lds[1][0][0], wv, lane);
  stage_half(Abase + (long)128 * K + 64, K, &lds[1][0][8192], wv, lane);
  stage_half(Bbase + 64, K, &lds[1][1][0], wv, lane);
  stage_half(Bbase + (long)128 * K + 64, K, &lds[1][1][8192], wv, lane);
  asm volatile("s_waitcnt vmcnt(8)" ::: "memory");   // K-tile 0 landed
  __builtin_amdgcn_s_barrier();
  GFENCE();

  for (int kt = 0; kt < NT; ++kt) {
    const int buf = kt & 1;
    const __bf16* Ah = &lds[buf][0][wr * 8192];        // wave's A half
    const __bf16* Bh = &lds[buf][1][(wc >> 1) * 8192]; // wave's B half
    const int brow0 = (wc & 1) << 6;
    const bool pre = (kt + 2 < NT);
    bf16x8 aF[4][2], bF[4][2];

    // ---------- phase 0: read A mh0 (8) + B n0,n1 (4); MFMA m0-3 x n0-1 ----------
#pragma unroll
    for (int m = 0; m < 4; ++m) {
      aF[m][0] = frag_ld(Ah, m * 16 + l16, 0, quad);
      aF[m][1] = frag_ld(Ah, m * 16 + l16, 1, quad);
    }
#pragma unroll
    for (int n = 0; n < 2; ++n) {
      bF[n][0] = frag_ld(Bh, brow0 + n * 16 + l16, 0, quad);
      bF[n][1] = frag_ld(Bh, brow0 + n * 16 + l16, 1, quad);
    }
    MIDBAR();
    __builtin_amdgcn_s_setprio(1);
#pragma unroll
    for (int m = 0; m < 4; ++m)
#pragma unroll
      for (int n = 0; n < 2; ++n) {
        acc[m][n] = __builtin_amdgcn_mfma_f32_16x16x32_bf16(aF[m][0], bF[n][0], acc[m][n], 0, 0, 0);
        acc[m][n] = __builtin_amdgcn_mfma_f32_16x16x32_bf16(aF[m][1], bF[n][1], acc[m][n], 0, 0, 0);
      }
    __builtin_amdgcn_s_setprio(0);
    ENDBAR();

    // ---------- phase 1: read B n2,n3 (4); MFMA m0-3 x n2-3 ----------
#pragma unroll
    for (int n = 2; n < 4; ++n) {
      bF[n][0] = frag_ld(Bh, brow0 + n * 16 + l16, 0, quad);
      bF[n][1] = frag_ld(Bh, brow0 + n * 16 + l16, 1, quad);
    }
    MIDBAR();
    __builtin_amdgcn_s_setprio(1);
#pragma unroll
    for (int m = 0; m < 4; ++m)
#pragma unroll
      for (int n = 2; n < 4; ++n) {
        acc[m][n] = __builtin_amdgcn_mfma_f32_16x16x32_bf16(aF[m][0], bF[n][0], acc[m][n], 0, 0, 0);
        acc[m][n] = __builtin_amdgcn_mfma_f32_16x16x32_bf16(aF[m][1], bF[n][1], acc[m][n], 0, 0, 0);
      }
    __builtin_amdgcn_s_setprio(0);
    ENDBAR();

    // ---------- phase 2: read A mh1 (8); stage B(kt+2); MFMA m4-7 x n2-3 ----------
#pragma unroll
    for (int m = 0; m < 4; ++m) {
      aF[m][0] = frag_ld(Ah, 64 + m * 16 + l16, 0, quad);
      aF[m][1] = frag_ld(Ah, 64 + m * 16 + l16, 1, quad);
    }
    if (pre) {  // B halves last read in phase 1 (all waves, via its barriers)
      const u16* p = Bbase + (long)(kt + 2) * 64;
      stage_half(p, K, &lds[buf][1][0], wv, lane);
      stage_half(p + (long)128 * K, K, &lds[buf][1][8192], wv, lane);
    }
    MIDBAR();
    __builtin_amdgcn_s_setprio(1);
#pragma unroll
    for (int m = 0; m < 4; ++m)
#pragma unroll
      for (int n = 2; n < 4; ++n) {
        acc[4 + m][n] = __builtin_amdgcn_mfma_f32_16x16x32_bf16(aF[m][0], bF[n][0], acc[4 + m][n], 0, 0, 0);
        acc[4 + m][n] = __builtin_amdgcn_mfma_f32_16x16x32_bf16(aF[m][1], bF[n][1], acc[4 + m][n], 0, 0, 0);
      }
    __builtin_amdgcn_s_setprio(0);
    ENDBAR();

    // ---------- phase 3: stage A(kt+2); MFMA m4-7 x n0-1; counted vmcnt ----------
    if (pre) {  // A halves last read in phase 2
      const u16* p = Abase + (long)(kt + 2) * 64;
      stage_half(p, K, &lds[buf][0][0], wv, lane);
      stage_half(p + (long)128 * K, K, &lds[buf][0][8192], wv, lane);
    }
    MIDBAR();
    __builtin_amdgcn_s_setprio(1);
#pragma unroll
    for (int m = 0; m < 4; ++m)
#pragma unroll
      for (int n = 0; n < 2; ++n) {
        acc[4 + m][n] = __builtin_amdgcn_mfma_f32_16x16x32_bf16(aF[m][0], bF[n][0], acc[4 + m][n], 0, 0, 0);
        acc[4 + m][n] = __builtin_amdgcn_mfma_f32_16x16x32_bf16(aF[m][1], bF[n][1], acc[4 + m][n], 0, 0, 0);
      }
    __builtin_amdgcn_s_setprio(0);
    if (pre) { asm volatile("s_waitcnt vmcnt(8)" ::: "memory"); }  // kt+1 landed
    else     { asm volatile("s_waitcnt vmcnt(0)" ::: "memory"); }  // tail drain
    ENDBAR();
  }

  // ---- epilogue ----
  const long colbase = (long)bn + wc * 64 + l16;
#pragma unroll
  for (int mt = 0; mt < 8; ++mt)
#pragma unroll
    for (int nt = 0; nt < 4; ++nt)
#pragma unroll
      for (int rr = 0; rr < 4; ++rr) {
        long row = bm + wr * 128 + mt * 16 + quad * 4 + rr;
        store_out(C, row * N + colbase + nt * 16, acc[mt][nt][rr]);
      }
}

// ---------------- RoPE on Q in place: qkv cols [0,2048) ----------------
__global__ void rope_q_k(u16* __restrict__ qkv, const float* __restrict__ cosT,
                         const float* __restrict__ sinT) {
  long i = (long)blockIdx.x * 256 + threadIdx.x;   // < B*S*16*64
  int j = i & 63;
  long rest = i >> 6;
  int h = rest & 15;
  long bs = rest >> 4;
  int s = bs & (S_LEN - 1);
  long base = bs * QKV_W + h * DHEAD + j;
  float x1 = bf2f(qkv[base]), x2 = bf2f(qkv[base + 64]);
  float c = cosT[s * 64 + j], sn = sinT[s * 64 + j];
  qkv[base] = f2bf(x1 * c - x2 * sn);
  qkv[base + 64] = f2bf(x2 * c + x1 * sn);
}

// ---- RoPE on K: qkv cols [2048,2560) -> Kb (B,4,S,128) ----
__global__ void rope_k_k(const u16* __restrict__ qkv, u16* __restrict__ Kb,
                         const float* __restrict__ cosT, const float* __restrict__ sinT) {
  long i = (long)blockIdx.x * 256 + threadIdx.x;   // < B*S*4*64
  int j = i & 63;
  long rest = i >> 6;
  int g = rest & 3;
  long bs = rest >> 2;
  int s = bs & (S_LEN - 1);
  int b = (int)(bs >> 11);
  long src = bs * QKV_W + 2048 + g * 128 + j;
  float x1 = bf2f(qkv[src]), x2 = bf2f(qkv[src + 64]);
  float c = cosT[s * 64 + j], sn = sinT[s * 64 + j];
  long dst = ((long)(b * NGROUPS + g) * S_LEN + s) * DHEAD + j;
  Kb[dst] = f2bf(x1 * c - x2 * sn);
  Kb[dst + 64] = f2bf(x2 * c + x1 * sn);
}

// ---- V transpose: qkv cols [2560,3072) -> Vt (B,4,128,S) ----
__global__ void v_trans_k(const u16* __restrict__ qkv, u16* __restrict__ Vt) {
  __shared__ u16 tile[32][33];
  int s0 = blockIdx.x * 32, d0 = blockIdx.y * 32;
  int bg = blockIdx.z;
  int b = bg >> 2, g = bg & 3;
  int tx = threadIdx.x, ty = threadIdx.y;
  for (int i = 0; i < 32; i += 8) {
    long s = s0 + ty + i;
    tile[ty + i][tx] = qkv[((long)b * S_LEN + s) * QKV_W + 2560 + g * 128 + d0 + tx];
  }
  __syncthreads();
  for (int i = 0; i < 32; i += 8) {
    int d = d0 + ty + i;
    Vt[((long)(b * NGROUPS + g) * DHEAD + d) * S_LEN + s0 + tx] = tile[tx][ty + i];
  }
}

// ---------------- Flash attention v5: 64-key chunks, paired tiles ----------
__global__ __launch_bounds__(256, 2) void attn_k5(
    const u16* __restrict__ Q,   // qkv (B,S,3072), cols [0,2048) post-rope
    const u16* __restrict__ Kb,  // (B,4,S,128)  post-rope
    const u16* __restrict__ Vt,  // (B,4,128,S)
    u16* __restrict__ ctx) {     // (B,S,16,128)
  __shared__ __align__(16) __bf16 Ks[2][64 * 128];   // 32 KB
  __shared__ __align__(16) __bf16 Vts[2][128 * 64];  // 32 KB
  __shared__ __align__(16) __bf16 Ps[64 * 64];       // 8 KB

  const int h = blockIdx.y, b = blockIdx.z, g = h >> 2;
  const int tid = threadIdx.x, wv = tid >> 6, lane = tid & 63;
  const int quad = lane >> 4, l16 = lane & 15;
  const float SCALE = 0.08838834764831845f;

  const long kbase = (long)(b * NGROUPS + g) * S_LEN * DHEAD;
  const long vbase = (long)(b * NGROUPS + g) * DHEAD * S_LEN;

  const int krow_off = lane >> 4;
  const int vrow_off = lane >> 3;

  const __bf16 oneb = (__bf16)((l16 == 0) ? 1.0f : 0.0f);
  const bf16x8 bones = {oneb, oneb, oneb, oneb, oneb, oneb, oneb, oneb};

  for (int pass = 0; pass < 2; ++pass) {
    const int tile = pass == 0 ? (int)blockIdx.x : 31 - (int)blockIdx.x;
    const int q0 = tile * 64;
    const int nch = tile + 1;   // 64-key chunks

    bf16x8 aq[4];
    {
      const u16* qp = Q + (long)(b * S_LEN + q0 + wv * 16 + l16) * QKV_W + h * DHEAD + quad * 8;
#pragma unroll
      for (int ds = 0; ds < 4; ++ds)
        aq[ds] = *(const bf16x8*)(qp + ds * 32);
    }

#pragma unroll
    for (int i = 0; i < 4; ++i) {
      int r0 = wv * 16 + i * 4;
      int row = r0 + krow_off;
      int c = l16 ^ (row & 15);
      llds16(Kb + kbase + (long)row * DHEAD + c * 8, &Ks[0][r0 * 128 + lane * 8]);
    }
#pragma unroll
    for (int i = 0; i < 4; ++i) {
      int d0 = wv * 32 + i * 8;
      int row = d0 + vrow_off;
      int c = (lane & 7) ^ (row & 7);
      llds16(Vt + vbase + (long)row * S_LEN + c * 8, &Vts[0][d0 * 64 + lane * 8]);
    }
    __syncthreads();

    f32x4 Oacc[9] = {};

    for (int kc = 0; kc < nch; ++kc) {
      const int cur = kc & 1;
      if (kc + 1 < nch) {
        const int nxt = cur ^ 1;
#pragma unroll
        for (int i = 0; i < 4; ++i) {
          int r0 = wv * 16 + i * 4;
          int row = r0 + krow_off;
          int c = l16 ^ (row & 15);
          llds16(Kb + kbase + (long)((kc + 1) * 64 + row) * DHEAD + c * 8,
                 &Ks[nxt][r0 * 128 + lane * 8]);
        }
#pragma unroll
        for (int i = 0; i < 4; ++i) {
          int d0 = wv * 32 + i * 8;
          int row = d0 + vrow_off;
          int c = (lane & 7) ^ (row & 7);
          llds16(Vt + vbase + (long)row * S_LEN + (kc + 1) * 64 + c * 8,
                 &Vts[nxt][d0 * 64 + lane * 8]);
        }
      }

      f32x4 sacc[4] = {};
#pragma unroll
      for (int ds = 0; ds < 4; ++ds) {
        int pos0 = ((ds * 4 + quad) ^ l16) * 8;
#pragma unroll
        for (int nt = 0; nt < 4; ++nt) {
          bf16x8 bk = *(const bf16x8*)&Ks[cur][(nt * 16 + l16) * 128 + pos0];
          sacc[nt] = __builtin_amdgcn_mfma_f32_16x16x32_bf16(aq[ds], bk, sacc[nt], 0, 0, 0);
        }
      }

#pragma unroll
      for (int nt = 0; nt < 4; ++nt)
#pragma unroll
        for (int r = 0; r < 4; ++r) {
          int qrow = q0 + wv * 16 + quad * 4 + r;
          int key = kc * 64 + nt * 16 + l16;
          float p = (key <= qrow) ? __expf(sacc[nt][r] * SCALE) : 0.f;
          int qlocal = quad * 4 + r;
          int chunk = nt * 2 + (l16 >> 3);
          int pos = chunk ^ (qlocal & 7);
          Ps[(wv * 16 + qlocal) * 64 + pos * 8 + (l16 & 7)] = (__bf16)p;
        }

      bf16x8 ap[2];
#pragma unroll
      for (int kf = 0; kf < 2; ++kf) {
        int pos = ((kf * 4 + quad) ^ (l16 & 7)) * 8;
        ap[kf] = *(const bf16x8*)&Ps[(wv * 16 + l16) * 64 + pos];
      }
#pragma unroll
      for (int nt = 0; nt < 8; ++nt)
#pragma unroll
        for (int kf = 0; kf < 2; ++kf) {
          int pos = ((kf * 4 + quad) ^ (l16 & 7)) * 8;
          bf16x8 bv = *(const bf16x8*)&Vts[cur][(nt * 16 + l16) * 64 + pos];
          Oacc[nt] = __builtin_amdgcn_mfma_f32_16x16x32_bf16(ap[kf], bv, Oacc[nt], 0, 0, 0);
        }
      Oacc[8] = __builtin_amdgcn_mfma_f32_16x16x32_bf16(ap[0], bones, Oacc[8], 0, 0, 0);
      Oacc[8] = __builtin_amdgcn_mfma_f32_16x16x32_bf16(ap[1], bones, Oacc[8], 0, 0, 0);

      __syncthreads();
    }

    float lsum[4];
#pragma unroll
    for (int r = 0; r < 4; ++r)
      lsum[r] = __shfl(Oacc[8][r], quad << 4, 64);

    const long obase = ((long)(b * S_LEN + q0 + wv * 16) * NHEADS + h) * DHEAD;
#pragma unroll
    for (int nt = 0; nt < 8; ++nt)
#pragma unroll
      for (int r = 0; r < 4; ++r) {
        int lrow = quad * 4 + r;
        ctx[obase + (long)lrow * NHEADS * DHEAD + nt * 16 + l16] =
            f2bf(Oacc[nt][r] / lsum[r]);
      }
  }
}

extern "C" void kernel_launch(void* const* d_in, const int* in_sizes, int n_in,
                              void* d_out, int out_size, void* d_ws, size_t ws_size,
                              hipStream_t stream) {
  const float* x   = (const float*)d_in[0];   // (B,S,2048) fp32
  const float* wq  = (const float*)d_in[1];   // (2048, 2048) fp32
  const float* wkv = (const float*)d_in[2];   // (2048, 1024) fp32
  const float* wd  = (const float*)d_in[3];   // (2048, 2048) fp32
  float* out = (float*)d_out;                 // (B,S,2048) fp32

  char* ws = (char*)d_ws;
  float* cosT  = (float*)(ws + 0);             //   524288 B
  float* sinT  = (float*)(ws + 524288);        //   524288 B
  u16* wqkvT = (u16*)(ws + 1048576);           // 12582912 B (3072 x 2048 bf16)
  u16* wdT   = (u16*)(ws + 13631488);          //  8388608 B (2048 x 2048 bf16)
  u16* xb    = (u16*)(ws + 22020096);          // 16777216 B (B*S, 2048) bf16
  u16* qkv   = (u16*)(ws + 38797312);          // 25165824 B (B*S, 3072) bf16
  u16* Kb    = (u16*)(ws + 63963136);          //  4194304 B (B,4,S,128) bf16
  u16* Vt    = (u16*)(ws + 68157440);          //  4194304 B (B,4,128,S) bf16
  u16* ctx   = (u16*)(ws + 72351744);          // 16777216 B (B,S,16,128) bf16
                                               // total 89128960 B

  rope_tables_k<<<512, 256, 0, stream>>>(cosT, sinT);
  cvt_f32_bf16<<<8192, 256, 0, stream>>>(x, xb);
  transpose_f32_bf16<<<dim3(64, 64), dim3(32, 8), 0, stream>>>(wq, wqkvT, 2048, 2048);
  transpose_f32_bf16<<<dim3(32, 64), dim3(32, 8), 0, stream>>>(wkv, wqkvT + (long)2048 * 2048, 2048, 1024);
  transpose_f32_bf16<<<dim3(64, 64), dim3(32, 8), 0, stream>>>(wd, wdT, 2048, 2048);

  // fused QKV projection: (B*S,2048) x (3072,2048)^T -> (B*S,3072)
  gemm_bt8<u16><<<dim3(12, 16), 512, 0, stream>>>(xb, wqkvT, qkv, 4096, 3072, 2048);

  rope_q_k<<<16384, 256, 0, stream>>>(qkv, cosT, sinT);
  rope_k_k<<<4096, 256, 0, stream>>>(qkv, Kb, cosT, sinT);
  v_trans_k<<<dim3(64, 4, 8), dim3(32, 8), 0, stream>>>(qkv, Vt);

  attn_k5<<<dim3(16, 16, 2), 256, 0, stream>>>(qkv, Kb, Vt, ctx);

  gemm_bt8<float><<<dim3(8, 16), 512, 0, stream>>>(ctx, wdT, out, 4096, 2048, 2048);
}